// Round 1
// baseline (40482.776 us; speedup 1.0000x reference)
//
#include <hip/hip_runtime.h>
#include <math.h>

// Problem constants (fixed by the reference)
#define N_NODES 16384
#define HID 512
#define G4 2048   // 4*HID
#define MAXC 4

// Dataflow config: 32 teams x 16 slices (wgs), 512 threads each. grid = 512
// = 2 wgs/CU (VGPR=128 -> exactly 2 blocks/CU; __launch_bounds__(512,4)
// forces the compiler to stay <=128 VGPR so residency is guaranteed).
// All wgs co-resident; teams claim nodes in increasing index order
// -> smallest-unfinished-node argument gives deadlock freedom.
// Rationale (R1): kernel is latency-bound (VALUBusy 6.8%, HBM 0.35%), one
// wg/CU left the CU idle during every LLC round trip. 2 wgs/CU halves the
// serial round count (1024 -> 512) and overlaps the per-node latencies.
#define T_TEAMS 32
#define S_WGS 16
#define NWG (T_TEAMS * S_WGS)   // 512
#define BLK 512            // threads per wg (8 waves)
#define NSUB 16            // e-chunks per wg
#define ECH 32             // e's per chunk  (NSUB*ECH = 512)
#define FPN 16             // flag words per node (one per slice, one 64B line)

#define AT_LD(p)    __hip_atomic_load((p), __ATOMIC_RELAXED, __HIP_MEMORY_SCOPE_AGENT)
#define AT_ST(p, v) __hip_atomic_store((p), (v), __ATOMIC_RELAXED, __HIP_MEMORY_SCOPE_AGENT)

__device__ __forceinline__ float sigm(float x) { return 1.0f / (1.0f + __expf(-x)); }

// ---------------------------------------------------------------------------
// Kernel 1: i2h = inputs @ i2h_weight^T + i2h_bias (unchanged — correct)
// ---------------------------------------------------------------------------
#define BK 16
__global__ void __launch_bounds__(256) gemm_i2h(
    const float* __restrict__ A, const float* __restrict__ B,
    const float* __restrict__ bias, float* __restrict__ C)
{
  __shared__ float As[BK][68];
  __shared__ float Bs[BK][68];
  const int tid = threadIdx.x;
  const int tx = tid & 15, ty = tid >> 4;
  const int rowBase = blockIdx.y * 64, colBase = blockIdx.x * 64;
  const int r = tid >> 2;
  const int kk = (tid & 3) << 2;
  float acc[4][4] = {};

  for (int k0 = 0; k0 < 512; k0 += BK) {
    float4 a4 = *(const float4*)&A[(size_t)(rowBase + r) * 512 + k0 + kk];
    float4 b4 = *(const float4*)&B[(size_t)(colBase + r) * 512 + k0 + kk];
    __syncthreads();
    As[kk + 0][r] = a4.x; As[kk + 1][r] = a4.y; As[kk + 2][r] = a4.z; As[kk + 3][r] = a4.w;
    Bs[kk + 0][r] = b4.x; Bs[kk + 1][r] = b4.y; Bs[kk + 2][r] = b4.z; Bs[kk + 3][r] = b4.w;
    __syncthreads();
#pragma unroll
    for (int k = 0; k < BK; k++) {
      float4 av = *(const float4*)&As[k][ty << 2];
      float4 bv = *(const float4*)&Bs[k][tx << 2];
      float a0 = av.x, a1 = av.y, a2 = av.z, a3 = av.w;
      float b0 = bv.x, b1 = bv.y, b2 = bv.z, b3 = bv.w;
      acc[0][0] += a0 * b0; acc[0][1] += a0 * b1; acc[0][2] += a0 * b2; acc[0][3] += a0 * b3;
      acc[1][0] += a1 * b0; acc[1][1] += a1 * b1; acc[1][2] += a1 * b2; acc[1][3] += a1 * b3;
      acc[2][0] += a2 * b0; acc[2][1] += a2 * b1; acc[2][2] += a2 * b2; acc[2][3] += a2 * b3;
      acc[3][0] += a3 * b0; acc[3][1] += a3 * b1; acc[3][2] += a3 * b2; acc[3][3] += a3 * b3;
    }
  }
#pragma unroll
  for (int i = 0; i < 4; i++) {
    const int row = rowBase + (ty << 2) + i;
    const int col = colBase + (tx << 2);
    float4 o;
    o.x = acc[i][0] + bias[col + 0];
    o.y = acc[i][1] + bias[col + 1];
    o.z = acc[i][2] + bias[col + 2];
    o.w = acc[i][3] + bias[col + 3];
    *(float4*)&C[(size_t)row * G4 + col] = o;
  }
}

// ---------------------------------------------------------------------------
// Gate dot-products: weights in registers, child h from LDS (broadcast reads).
// ---------------------------------------------------------------------------
template<int NC>
__device__ __forceinline__ void gates_lds(
    const float (*hch)[HID], int e0,
    const float4* wi, const float4* wu, const float4* wo, const float* wf,
    float& aI, float& aU, float& aO, float (&aF)[4])
{
#pragma unroll
  for (int q = 0; q < 8; q++) {
    float4 c0 = *(const float4*)&hch[0][e0 + 4 * q];
    float4 c1 = {0,0,0,0}, c2 = {0,0,0,0}, c3 = {0,0,0,0};
    if constexpr (NC > 1) c1 = *(const float4*)&hch[1][e0 + 4 * q];
    if constexpr (NC > 2) c2 = *(const float4*)&hch[2][e0 + 4 * q];
    if constexpr (NC > 3) c3 = *(const float4*)&hch[3][e0 + 4 * q];
    float sx = c0.x, sy = c0.y, sz = c0.z, sw = c0.w;
    if constexpr (NC > 1) { sx += c1.x; sy += c1.y; sz += c1.z; sw += c1.w; }
    if constexpr (NC > 2) { sx += c2.x; sy += c2.y; sz += c2.z; sw += c2.w; }
    if constexpr (NC > 3) { sx += c3.x; sy += c3.y; sz += c3.z; sw += c3.w; }
    aI += wi[q].x * sx; aI += wi[q].y * sy; aI += wi[q].z * sz; aI += wi[q].w * sw;
    aU += wu[q].x * sx; aU += wu[q].y * sy; aU += wu[q].z * sz; aU += wu[q].w * sw;
    aO += wo[q].x * sx; aO += wo[q].y * sy; aO += wo[q].z * sz; aO += wo[q].w * sw;
    aF[0] += wf[4*q+0] * c0.x; aF[0] += wf[4*q+1] * c0.y;
    aF[0] += wf[4*q+2] * c0.z; aF[0] += wf[4*q+3] * c0.w;
    if constexpr (NC > 1) {
      aF[1] += wf[4*q+0] * c1.x; aF[1] += wf[4*q+1] * c1.y;
      aF[1] += wf[4*q+2] * c1.z; aF[1] += wf[4*q+3] * c1.w;
    }
    if constexpr (NC > 2) {
      aF[2] += wf[4*q+0] * c2.x; aF[2] += wf[4*q+1] * c2.y;
      aF[2] += wf[4*q+2] * c2.z; aF[2] += wf[4*q+3] * c2.w;
    }
    if constexpr (NC > 3) {
      aF[3] += wf[4*q+0] * c3.x; aF[3] += wf[4*q+1] * c3.y;
      aF[3] += wf[4*q+2] * c3.z; aF[3] += wf[4*q+3] * c3.w;
    }
  }
}

// ---------------------------------------------------------------------------
// Kernel 2: persistent dataflow recurrence.
// ALL cross-wg traffic (H, C, flags) uses relaxed AGENT-scope atomics — these
// lower to per-access device-coherent loads/stores served at the LLC, with NO
// bulk L1/L2 invalidate/writeback.
// Producer order: data stores -> s_waitcnt(0) -> flag store.
// Consumer order: flag poll (one coalesced wave-wide load covering all
// children x all slices) -> barrier -> data loads. No RMW, no fences.
// __launch_bounds__(512,4): 4 waves/SIMD = 16 waves/CU = 2 blocks/CU min,
// caps VGPR at 128 (current allocation is exactly 128) -> all 512 wgs
// co-resident, which the deadlock-freedom argument requires.
// ---------------------------------------------------------------------------
__global__ void __launch_bounds__(BLK, 4) recur(
    const float* __restrict__ i2h,
    const float* __restrict__ hs2h_w, const float* __restrict__ hc2h_w,
    const float* __restrict__ hs2h_b, const float* __restrict__ hc2h_b,
    const int* __restrict__ child_idx, const int* __restrict__ child_mask,
    float* Hout, float* Cout, int* flags)
{
  __shared__ float hch[MAXC][HID];     // 8 KB: children h
  __shared__ float red[7][NSUB][32];   // 14 KB: partial-dot reduction

  const int tid = threadIdx.x;
  const int wg = blockIdx.x;
  const int team = wg & (T_TEAMS - 1);   // 0..31
  const int slice = wg / T_TEAMS;        // 0..15 : this wg's 32 hidden dims
  const int rr = tid & 31;
  const int sub = tid >> 5;            // 0..15 : e-chunk
  const int rp = slice * 32 + rr;
  const int e0 = sub * ECH;

  // ---- one-time: weights into registers (128 floats/thread) ----
  float4 wi[8], wu[8], wo[8];
  float wf[32];
#pragma unroll
  for (int q = 0; q < 8; q++) {
    wi[q] = *(const float4*)&hs2h_w[(size_t)rp * HID + e0 + 4 * q];
    wu[q] = *(const float4*)&hs2h_w[(size_t)(512 + rp) * HID + e0 + 4 * q];
    wo[q] = *(const float4*)&hs2h_w[(size_t)(1024 + rp) * HID + e0 + 4 * q];
  }
#pragma unroll
  for (int e = 0; e < 32; e++)
    wf[e] = hc2h_w[(size_t)(e0 + e) * HID + rp];

  // ---- one-time: epilogue biases (wave0 / tid<32 only) ----
  const int rpp = slice * 32 + tid;    // valid only for tid<32
  float bI = 0.f, bU = 0.f, bO = 0.f, bF = 0.f;
  if (tid < 32) {
    bI = hs2h_b[rpp]; bU = hs2h_b[512 + rpp];
    bO = hs2h_b[1024 + rpp]; bF = hc2h_b[rpp];
  }

  for (int j = team; j < N_NODES; j += T_TEAMS) {
    const int4 ci = *(const int4*)&child_idx[j * 4];
    const int4 cm = *(const int4*)&child_mask[j * 4];
    const int nc = cm.x + cm.y + cm.z + cm.w;   // mask is a prefix
    const int cix[4] = {ci.x, ci.y, ci.z, ci.w};

    // prefetch i2h (normal cached loads; independent of children)
    float ipre = 0.f, fpre = 0.f, upre = 0.f, opre = 0.f;
    if (tid < 32) {
      const size_t jb = (size_t)j * G4;
      ipre = i2h[jb + rpp];
      fpre = i2h[jb + 512 + rpp];
      upre = i2h[jb + 1024 + rpp];
      opre = i2h[jb + 1536 + rpp];
    }

    float aI = 0.f, aU = 0.f, aO = 0.f, aF[4] = {0.f, 0.f, 0.f, 0.f};
    float cC[4] = {0.f, 0.f, 0.f, 0.f};

    if (nc > 0) {
      // ---- readiness: wave0 polls ALL children x ALL slices in one load ----
      if (tid < 64) {
        const int k = tid >> 4, s = tid & 15;
        const int cj = (k < nc) ? cix[k] : cix[0];
        int* fp = flags + cj * FPN + s;
        for (;;) {
          const int v = AT_LD(fp);
          const bool ok = (k >= nc) || (v != 0);
          if (__ballot(ok) == ~0ull) break;
        }
      }
      __syncthreads();  // B1: readiness broadcast (also LDS WAR protection)

      // ---- cooperative child-h stage -> LDS (coalesced LLC loads) ----
#pragma unroll
      for (int k = 0; k < MAXC; k++)
        if (k < nc) hch[k][tid] = AT_LD(Hout + (size_t)cix[k] * HID + tid);
      // wave0: prefetch child C for the epilogue (overlaps gates)
      if (tid < 32) {
#pragma unroll
        for (int k = 0; k < MAXC; k++)
          if (k < nc) cC[k] = AT_LD(Cout + (size_t)cix[k] * HID + rpp);
      }
      __syncthreads();  // B2: hch ready

      switch (nc) {
        case 1: gates_lds<1>(hch, e0, wi, wu, wo, wf, aI, aU, aO, aF); break;
        case 2: gates_lds<2>(hch, e0, wi, wu, wo, wf, aI, aU, aO, aF); break;
        case 3: gates_lds<3>(hch, e0, wi, wu, wo, wf, aI, aU, aO, aF); break;
        default: gates_lds<4>(hch, e0, wi, wu, wo, wf, aI, aU, aO, aF); break;
      }
      red[0][sub][rr] = aI;    red[1][sub][rr] = aU;    red[2][sub][rr] = aO;
      red[3][sub][rr] = aF[0]; red[4][sub][rr] = aF[1];
      red[5][sub][rr] = aF[2]; red[6][sub][rr] = aF[3];
      __syncthreads();  // B3: red ready
    }

    if (tid < 32) {
      float sI = 0.f, sU = 0.f, sO = 0.f;
      float sF0 = 0.f, sF1 = 0.f, sF2 = 0.f, sF3 = 0.f;
      if (nc > 0) {
#pragma unroll
        for (int s = 0; s < NSUB; s++) {
          sI += red[0][s][tid]; sU += red[1][s][tid]; sO += red[2][s][tid];
          sF0 += red[3][s][tid]; sF1 += red[4][s][tid];
          sF2 += red[5][s][tid]; sF3 += red[6][s][tid];
        }
      }
      const float ig = ipre + bI + sI;
      const float ug = upre + bU + sU;
      const float og = opre + bO + sO;
      float c = sigm(ig) * tanhf(ug);
      if (nc > 0) c += sigm(fpre + bF + sF0) * cC[0];
      if (nc > 1) c += sigm(fpre + bF + sF1) * cC[1];
      if (nc > 2) c += sigm(fpre + bF + sF2) * cC[2];
      if (nc > 3) c += sigm(fpre + bF + sF3) * cC[3];
      const float h = sigm(og) * tanhf(c);
      AT_ST(Hout + (size_t)j * HID + rpp, h);
      AT_ST(Cout + (size_t)j * HID + rpp, c);
    }
    // order: data stores reach the LLC before the flag store issues.
    asm volatile("" ::: "memory");
    __builtin_amdgcn_s_waitcnt(0);
    asm volatile("" ::: "memory");
    if (tid == 0)
      AT_ST(flags + j * FPN + slice, 1);
  }
}

// ---------------------------------------------------------------------------
// Workspace: [0,128MB) i2h ; [128MB, +1MB) flags (16 int32 per node)
// ---------------------------------------------------------------------------
extern "C" void kernel_launch(void* const* d_in, const int* in_sizes, int n_in,
                              void* d_out, int out_size, void* d_ws, size_t ws_size,
                              hipStream_t stream) {
  const float* inputs    = (const float*)d_in[0];
  const float* i2h_w     = (const float*)d_in[1];
  const float* i2h_b     = (const float*)d_in[2];
  const float* hs2h_w    = (const float*)d_in[3];
  const float* hs2h_b    = (const float*)d_in[4];
  const float* hc2h_w    = (const float*)d_in[5];
  const float* hc2h_b    = (const float*)d_in[6];
  const int*   child_idx = (const int*)d_in[7];
  const int*   child_mask= (const int*)d_in[8];

  float* Hout = (float*)d_out;
  float* Cout = Hout + (size_t)N_NODES * HID;

  char* ws = (char*)d_ws;
  const size_t i2h_bytes = (size_t)N_NODES * G4 * sizeof(float);
  float* i2h = (float*)ws;
  int*   flags = (int*)(ws + i2h_bytes);

  hipMemsetAsync(flags, 0, N_NODES * FPN * sizeof(int), stream);

  dim3 ggrid(G4 / 64, N_NODES / 64);
  gemm_i2h<<<ggrid, 256, 0, stream>>>(inputs, i2h_w, i2h_b, i2h);
  recur<<<NWG, BLK, 0, stream>>>(i2h, hs2h_w, hc2h_w, hs2h_b, hc2h_b,
                                 child_idx, child_mask, Hout, Cout, flags);
}